// Round 6
// baseline (2667.318 us; speedup 1.0000x reference)
//
#include <hip/hip_runtime.h>
#include <hip/hip_bf16.h>

// Bidirectional LSTM, B=32 T=512 D=512 U=512, fp32 in/out, bf16 MFMA internals.
// Phase 1: xg = x @ [Wf||Wb] + b  (bf16 MFMA GEMM, permuted columns)
// Phase 2: persistent recurrence, 32 groups/direction, U^T in registers.
//          R6: FLAG-FREE sync. h exchanged through 3 rotating IC slots; fresh
//          data detected by polling for absence of poison (0x7F80 = +inf bf16,
//          impossible for h = o*tanh(c), |h|<1). The successful poll IS the
//          staging fetch -> critical path = h-store visible + 1 poll RT.
//          (R2 learned: agent fences = L2 wb/inv, 17us/step. R3: agent-atomic
//          IC RT ~= 1us. R5: flags + separate staging = ~4 RT = 3.9us/step.)
// Phase 3: out = fwd + bwd

typedef __attribute__((ext_vector_type(8))) __bf16 bf16x8;
typedef __attribute__((ext_vector_type(4))) __bf16 bf16x4;
typedef __attribute__((ext_vector_type(4))) float fvec4;

#define AS_G(p) ((const __attribute__((address_space(1))) void*)(p))
#define AS_L(p) ((__attribute__((address_space(3))) void*)(p))

#define POISON32 0x7F807F80u   // two +inf bf16

__device__ __forceinline__ float sigm(float x) {
  return __builtin_amdgcn_rcpf(1.f + __expf(-x));
}
__device__ __forceinline__ float tanh_f(float x) {
  return 1.f - 2.f * __builtin_amdgcn_rcpf(__expf(2.f * x) + 1.f);
}

// coherent 4B store (two packed bf16), relaxed agent scope
__device__ __forceinline__ void st_u32(unsigned int* p, unsigned int v) {
  __hip_atomic_store(p, v, __ATOMIC_RELAXED, __HIP_MEMORY_SCOPE_AGENT);
}
__device__ __forceinline__ void st_h4(__bf16* p, float h0, float h1) {
  union { __bf16 h[2]; unsigned int u; } pk;
  pk.h[0] = (__bf16)h0;
  pk.h[1] = (__bf16)h1;
  st_u32((unsigned int*)p, pk.u);
}

// ---------------- conversions ----------------

__global__ void k_convert_x(const float* __restrict__ x, __bf16* __restrict__ xb) {
  size_t i = ((size_t)blockIdx.x * 256 + threadIdx.x) * 8;
  fvec4 a = *(const fvec4*)(x + i);
  fvec4 b = *(const fvec4*)(x + i + 4);
  bf16x8 o;
#pragma unroll
  for (int j = 0; j < 4; ++j) { o[j] = (__bf16)a[j]; o[4 + j] = (__bf16)b[j]; }
  *(bf16x8*)(xb + i) = o;
}

// dst[p][k] = src[k][orig(p)] as bf16. Permutation: p = g*64 + w*16 + jj*4 + gate
// <-> orig = gate*512 + g*16 + w*4 + jj  (Keras gate order i,f,c,o).
__global__ void k_build_T(const float* __restrict__ src, const float* __restrict__ bvec,
                          __bf16* __restrict__ dst, float* __restrict__ bias_out) {
  int p = blockIdx.x;
  int g = p >> 6, r = p & 63, w = r >> 4, q = r & 15, jj = q >> 2, gate = q & 3;
  int orig = gate * 512 + g * 16 + w * 4 + jj;
  for (int k = threadIdx.x; k < 512; k += 256)
    dst[(size_t)p * 512 + k] = (__bf16)src[(size_t)k * 2048 + orig];
  if (bias_out && threadIdx.x == 0) bias_out[p] = bvec[orig];
}

// hbuf layout: [2 dir][3 slot][16 ks][32 row][32 col] bf16.
// slot 0 <- z (h_0); slots 1,2 <- poison.
__global__ void k_init_h(const float* __restrict__ z, __bf16* __restrict__ hbuf) {
  int idx = blockIdx.x * 256 + threadIdx.x;      // 0..98303
  int dir = idx / 49152, rem = idx % 49152;
  int slot = rem >> 14, e = rem & 16383;
  int ks = e >> 10, row = (e >> 5) & 31, c = e & 31;
  union { unsigned short u; __bf16 h; } pz; pz.u = 0x7F80;
  hbuf[(size_t)dir * 49152 + rem] =
      (slot == 0) ? (__bf16)z[row * 512 + ks * 32 + c] : pz.h;
}

// ---------------- input GEMM: [16384,512] x [4096,512]^T -> bf16 [16384,4096] ----------------

__global__ __launch_bounds__(256, 2) void k_gemm_xw(
    const __bf16* __restrict__ A,   // [16384][512] bf16
    const __bf16* __restrict__ Bt,  // [4096][512] bf16 (permuted W^T)
    const float* __restrict__ bias, // [4096] permuted
    __bf16* __restrict__ C)         // [16384][4096]
{
  __shared__ __align__(16) __bf16 As[128 * 32];
  __shared__ __align__(16) __bf16 Bs[128 * 32];
  const int tid = threadIdx.x;
  const int w = tid >> 6, lane = tid & 63, quad = lane >> 4, l15 = lane & 15;
  const int m0 = blockIdx.y * 128, n0 = blockIdx.x * 128;
  const int wm = w & 1, wn = w >> 1;

  fvec4 acc[4][4];
  const fvec4 zero = {0.f, 0.f, 0.f, 0.f};
#pragma unroll
  for (int i = 0; i < 4; ++i)
#pragma unroll
    for (int j = 0; j < 4; ++j) acc[i][j] = zero;

  for (int kb = 0; kb < 16; ++kb) {
    const int k0 = kb * 32;
#pragma unroll
    for (int i = 0; i < 2; ++i) {
      const int c = (i * 4 + w) * 64 + lane;      // 16B chunk id, 0..511
      const int row = c >> 2, kk = (c & 3) * 8;
      __builtin_amdgcn_global_load_lds(AS_G(A + (size_t)(m0 + row) * 512 + k0 + kk),
                                       AS_L(As + (size_t)(i * 4 + w) * 512), 16, 0, 0);
      __builtin_amdgcn_global_load_lds(AS_G(Bt + (size_t)(n0 + row) * 512 + k0 + kk),
                                       AS_L(Bs + (size_t)(i * 4 + w) * 512), 16, 0, 0);
    }
    __syncthreads();
    bf16x8 af[4], bfr[4];
#pragma unroll
    for (int mt = 0; mt < 4; ++mt)
      af[mt] = *(const bf16x8*)(As + (wm * 64 + mt * 16 + l15) * 32 + quad * 8);
#pragma unroll
    for (int nt = 0; nt < 4; ++nt)
      bfr[nt] = *(const bf16x8*)(Bs + (wn * 64 + nt * 16 + l15) * 32 + quad * 8);
#pragma unroll
    for (int mt = 0; mt < 4; ++mt)
#pragma unroll
      for (int nt = 0; nt < 4; ++nt)
        acc[mt][nt] = __builtin_amdgcn_mfma_f32_16x16x32_bf16(af[mt], bfr[nt], acc[mt][nt], 0, 0, 0);
    __syncthreads();
  }

#pragma unroll
  for (int nt = 0; nt < 4; ++nt) {
    const int col = n0 + wn * 64 + nt * 16 + l15;
    const float bv = bias[col];
#pragma unroll
    for (int mt = 0; mt < 4; ++mt) {
      const int rowb = m0 + wm * 64 + mt * 16 + quad * 4;
#pragma unroll
      for (int r = 0; r < 4; ++r)
        C[(size_t)(rowb + r) * 4096 + col] = (__bf16)(acc[mt][nt][r] + bv);
    }
  }
}

// ---------------- persistent recurrence ----------------
// 64 blocks: dir = blk>>5, group g = blk&31 owns h-cols [g*16, g*16+16).
// Step kt: poll slot kt%3 until poison-free (per-4B checks; 4B units are the
// producer-store atomic granule) -> poison own region in slot (kt+2)%3 ->
// ds_write staging (XOR-swizzled, conflict-free) -> barrier -> MFMA + gates ->
// h store into slot (kt+1)%3 -> out stores -> barrier (protects h_lds, drains).
// Safety: poison drained (vmcnt0 @ barriers) before h_{kt+1} issues => any
// reader that entered step kt+2 observes poison-or-newer, never stale h.

__global__ __launch_bounds__(256, 1) void k_lstm_rec(
    const __bf16* __restrict__ xg,  // [16384][4096] permuted
    const float* __restrict__ z,    // [32][512]
    const __bf16* __restrict__ UT,  // [2][2048][512] permuted
    __bf16* __restrict__ hbuf,      // [2][3][16384] chunked
    float* __restrict__ outf,       // d_out [32][512][512] (fwd)
    __bf16* __restrict__ outb)      // ws [32][512][512] (bwd)
{
  const int blk = blockIdx.x, dir = blk >> 5, g = blk & 31;
  const int tid = threadIdx.x, w = tid >> 6, lane = tid & 63;
  const int quad = lane >> 4, l15 = lane & 15;
  __shared__ __align__(16) __bf16 h_lds[16384];   // 32 KB, single buffer
  __shared__ __align__(16) float gates[32][68];

  // U^T slice resident in registers for all 512 steps (64 VGPRs)
  bf16x8 breg[16];
  {
    const __bf16* up = UT + ((size_t)dir * 2048 + g * 64 + w * 16 + l15) * 512 + quad * 8;
#pragma unroll
    for (int ks = 0; ks < 16; ++ks) breg[ks] = *(const bf16x8*)(up + ks * 32);
  }

  const int b = lane >> 1, jpair = lane & 1;
  const int hcol = g * 16 + w * 4 + jpair * 2;
  float c0 = z[b * 512 + hcol];
  float c1 = z[b * 512 + hcol + 1];
  __bf16* hbase = hbuf + (size_t)dir * 49152;
  // producer store offset in chunked layout (elements)
  const int stoff = (g >> 1) * 1024 + b * 32 + (g & 1) * 16 + w * 4 + jpair * 2;
  // staging: this lane's linear element offset base (wave quarter)
  const int stage_off = w * 4096 + lane * 8;
  // LDS swizzle: chunk' = chunk ^ ((row>>1)&3) -> staging writes and fragment
  // reads both cover all 32 banks (R5: conflicts 1.78e7 -> 1.05e6)
  const int swz8 = ((lane & 3) ^ ((lane >> 3) & 3)) * 8;
  const int fr_swz = ((l15 >> 1) & 3);
  const fvec4 zero = {0.f, 0.f, 0.f, 0.f};

  for (int kt = 0; kt < 512; ++kt) {
    const int t = dir ? (511 - kt) : kt;
    const int slot_r = kt % 3, slot_w = (kt + 1) % 3, slot_p = (kt + 2) % 3;

    // prefetch xg tile (cached, independent of h) before the wait
    const bf16x8 xv = *(const bf16x8*)(xg + (size_t)(b * 512 + t) * 4096 +
                                       dir * 2048 + g * 64 + w * 16 + jpair * 8);

    // ---- poll slot_r: 16 pipelined 8B coherent loads; clean => data in regs ----
    unsigned long long tmp[16];
    {
      const unsigned long long* src =
          (const unsigned long long*)(hbase + slot_r * 16384 + stage_off);
      bool dirty;
      do {
#pragma unroll
        for (int it = 0; it < 8; ++it) {
          tmp[2 * it]     = __hip_atomic_load(src + it * 128,
                              __ATOMIC_RELAXED, __HIP_MEMORY_SCOPE_AGENT);
          tmp[2 * it + 1] = __hip_atomic_load(src + it * 128 + 1,
                              __ATOMIC_RELAXED, __HIP_MEMORY_SCOPE_AGENT);
        }
        dirty = false;
#pragma unroll
        for (int j = 0; j < 16; ++j) {
          dirty |= ((unsigned int)tmp[j] == POISON32);
          dirty |= ((unsigned int)(tmp[j] >> 32) == POISON32);
        }
      } while (dirty);
    }

    // poison own producer region in slot_p (safe: all blocks finished step kt-1;
    // drained by the barriers below before h_{kt+1} is published)
    if (kt < 511)
      st_u32((unsigned int*)(hbase + slot_p * 16384 + stoff), POISON32);

    // ---- stage to LDS (XOR-swizzled) ----
#pragma unroll
    for (int it = 0; it < 8; ++it) {
      union { unsigned long long u[2]; bf16x8 v; } cv;
      cv.u[0] = tmp[2 * it];
      cv.u[1] = tmp[2 * it + 1];
      // dst: ks = w*4 + it/2, row = (it&1)*16 + lane/4, chunk' swizzled
      *(bf16x8*)(h_lds + (w * 4 + (it >> 1)) * 1024 +
                 ((it & 1) * 16 + (lane >> 2)) * 32 + swz8) = cv.v;
    }
    __syncthreads();   // staging visible to all waves; drains poison stores

    fvec4 acc0 = zero, acc1 = zero;
#pragma unroll 8
    for (int ks = 0; ks < 16; ++ks) {
      bf16x8 a0 = *(const bf16x8*)(h_lds + ks * 1024 + l15 * 32 +
                                   ((quad ^ fr_swz) * 8));
      bf16x8 a1 = *(const bf16x8*)(h_lds + ks * 1024 + (16 + l15) * 32 +
                                   ((quad ^ fr_swz) * 8));
      acc0 = __builtin_amdgcn_mfma_f32_16x16x32_bf16(a0, breg[ks], acc0, 0, 0, 0);
      acc1 = __builtin_amdgcn_mfma_f32_16x16x32_bf16(a1, breg[ks], acc1, 0, 0, 0);
    }

    // transpose gates within the wave's private LDS region (cols w*16..w*16+16)
#pragma unroll
    for (int r = 0; r < 4; ++r) {
      gates[quad * 4 + r][w * 16 + l15] = acc0[r];
      gates[16 + quad * 4 + r][w * 16 + l15] = acc1[r];
    }
    const fvec4 gA = *(const fvec4*)&gates[b][w * 16 + jpair * 8];
    const fvec4 gB = *(const fvec4*)&gates[b][w * 16 + jpair * 8 + 4];

    float xf[8];
#pragma unroll
    for (int j = 0; j < 8; ++j) xf[j] = (float)xv[j];

    float ii = sigm(gA[0] + xf[0]);
    float ff = sigm(gA[1] + xf[1]);
    float cc = tanh_f(gA[2] + xf[2]);
    float oo = sigm(gA[3] + xf[3]);
    c0 = ff * c0 + ii * cc;
    const float h0 = oo * tanh_f(c0);

    ii = sigm(gB[0] + xf[4]);
    ff = sigm(gB[1] + xf[5]);
    cc = tanh_f(gB[2] + xf[6]);
    oo = sigm(gB[3] + xf[7]);
    c1 = ff * c1 + ii * cc;
    const float h1 = oo * tanh_f(c1);

    // publish h slice (critical path): coherent 4B store into slot_w
    if (kt < 511)
      st_h4(hbase + slot_w * 16384 + stoff, h0, h1);

    // out stores off the critical path
    const size_t oidx = (size_t)(b * 512 + t) * 512 + hcol;
    if (dir == 0) {
      outf[oidx] = h0;
      outf[oidx + 1] = h1;
    } else {
      outb[oidx] = (__bf16)h0;
      outb[oidx + 1] = (__bf16)h1;
    }

    __syncthreads();   // protect h_lds for next staging; drains all stores
  }
}

// ---------------- final merge ----------------

__global__ void k_add_bwd(float* __restrict__ out, const __bf16* __restrict__ outb) {
  size_t i = ((size_t)blockIdx.x * 256 + threadIdx.x) * 4;
  if (i >= (size_t)32 * 512 * 512) return;
  fvec4 o = *(const fvec4*)(out + i);
  bf16x4 bv = *(const bf16x4*)(outb + i);
#pragma unroll
  for (int j = 0; j < 4; ++j) o[j] += (float)bv[j];
  *(fvec4*)(out + i) = o;
}

// ---------------- host ----------------

extern "C" void kernel_launch(void* const* d_in, const int* in_sizes, int n_in,
                              void* d_out, int out_size, void* d_ws, size_t ws_size,
                              hipStream_t stream) {
  const float* x  = (const float*)d_in[0];
  const float* z  = (const float*)d_in[1];
  const float* Wf = (const float*)d_in[2];
  const float* Uf = (const float*)d_in[3];
  const float* bf = (const float*)d_in[4];
  const float* Wb = (const float*)d_in[5];
  const float* Ub = (const float*)d_in[6];
  const float* bb = (const float*)d_in[7];
  float* out = (float*)d_out;
  char* ws = (char*)d_ws;

  size_t off = 0;
  __bf16* xg    = (__bf16*)(ws + off); off += (size_t)16384 * 4096 * 2;   // 134 MB
  __bf16* UT    = (__bf16*)(ws + off); off += (size_t)2 * 2048 * 512 * 2; // 4 MB
  __bf16* hbuf  = (__bf16*)(ws + off); off += (size_t)2 * 3 * 16384 * 2;  // 192 KB
  float*  biasp = (float*)(ws + off);  off += 4096 * 4;
  char* uni = ws + off;
  __bf16* xb   = (__bf16*)uni;                               // phase 1
  __bf16* WT   = (__bf16*)(uni + (size_t)16384 * 512 * 2);   // phase 1
  __bf16* outb = (__bf16*)uni;                               // phase 2 (aliases xb)

  k_convert_x<<<4096, 256, 0, stream>>>(x, xb);
  k_build_T<<<2048, 256, 0, stream>>>(Wf, bf, WT, biasp);
  k_build_T<<<2048, 256, 0, stream>>>(Wb, bb, WT + (size_t)2048 * 512, biasp + 2048);
  k_build_T<<<2048, 256, 0, stream>>>(Uf, nullptr, UT, nullptr);
  k_build_T<<<2048, 256, 0, stream>>>(Ub, nullptr, UT + (size_t)2048 * 512, nullptr);
  k_init_h<<<384, 256, 0, stream>>>(z, hbuf);
  k_gemm_xw<<<dim3(32, 128), 256, 0, stream>>>(xb, WT, biasp, xg);
  k_lstm_rec<<<64, 256, 0, stream>>>(xg, z, UT, hbuf, out, outb);
  k_add_bwd<<<8192, 256, 0, stream>>>(out, outb);
}